// Round 1
// baseline (17988.666 us; speedup 1.0000x reference)
//
#include <hip/hip_runtime.h>
#include <cstdint>
#include <cstddef>

typedef __attribute__((ext_vector_type(8))) short short8;
typedef __attribute__((ext_vector_type(4))) short short4v;
typedef __attribute__((ext_vector_type(4))) float f32x4;

#define TT 2048
#define BB 32
#define HH 512
#define CH 32                 // scan steps per pipeline chunk
#define NCHUNK (TT / CH)      // 64 chunks
#define NHELP 64              // helper WGs for the streamed xin1 GEMM

__device__ inline short f2bf(float f) {
  union { float f; unsigned u; } v; v.f = f;
  unsigned r = v.u + 0x7fffu + ((v.u >> 16) & 1u);
  return (short)(r >> 16);
}
__device__ inline float bf2f(short s) {
  union { unsigned u; float f; } v; v.u = ((unsigned)(unsigned short)s) << 16;
  return v.f;
}

// LDS-only barrier: drains ds ops (lgkmcnt) but NOT global loads/stores
// (vmcnt), so xin prefetches and hall stores stay in flight across steps.
__device__ inline void barrier_lds() {
  asm volatile("s_waitcnt lgkmcnt(0)\n\ts_barrier" ::: "memory");
}

// xin swizzled element index for (t, b, c):
//   wg=b>>4, bl=b&15(=l16), wv=c>>6, ct=(c>>4)&3, q=(c>>2)&3, r=c&3, lane=q*16+bl
//   idx = ((((t*2+wg)*8+wv)*4+ct)*64 + lane)*4 + r

// ---------------- weight fp32 -> bf16 conversion ----------------
__global__ void convert_weights(const float* __restrict__ w0, const float* __restrict__ w1,
                                const float* __restrict__ w2, const float* __restrict__ w3,
                                const float* __restrict__ w4, short* __restrict__ dst) {
  int i = blockIdx.x * 256 + threadIdx.x;
  if (i >= 1048576) return;
  const float* src; int off;
  if (i < 131072)      { src = w0; off = i; }
  else if (i < 393216) { src = w1; off = i - 131072; }
  else if (i < 655360) { src = w2; off = i - 393216; }
  else if (i < 917504) { src = w3; off = i - 655360; }
  else                 { src = w4; off = i - 917504; }
  dst[i] = f2bf(src[off]);
}

// ---------------- bf16 MFMA GEMM, C = A @ B^T + bias ----------------
template<int A_XF32, int OUT_SW, int RESID>
__global__ __launch_bounds__(256) void gemm_bt(const void* __restrict__ Ap,
    const short* __restrict__ Bw, const float* __restrict__ bias,
    const float* __restrict__ resid, void* __restrict__ Cp, int M, int N, int K) {
  __shared__ short As[64][40];
  __shared__ short Bs[64][40];
  int tid = threadIdx.x;
  int m0 = blockIdx.x * 64, n0 = blockIdx.y * 64;
  int w = tid >> 6, lane = tid & 63;
  int wm = w >> 1, wn = w & 1;
  int quad = lane >> 4, l16 = lane & 15;
  f32x4 acc[2][2];
#pragma unroll
  for (int i = 0; i < 2; i++)
#pragma unroll
    for (int j = 0; j < 2; j++) acc[i][j] = (f32x4){0.f, 0.f, 0.f, 0.f};
  int lr = tid >> 2, lk = (tid & 3) * 8;
  for (int kk = 0; kk < K; kk += 32) {
    __syncthreads();
    {
      int rl = m0 + lr;
      if (A_XF32) {
        const float* A = (const float*)Ap;
        size_t phys = ((size_t)(rl & 31) * TT + (rl >> 5)) * K;
        const float4* p = (const float4*)(A + phys + kk + lk);
        float4 a0 = p[0], a1 = p[1];
        short8 v;
        v[0] = f2bf(a0.x); v[1] = f2bf(a0.y); v[2] = f2bf(a0.z); v[3] = f2bf(a0.w);
        v[4] = f2bf(a1.x); v[5] = f2bf(a1.y); v[6] = f2bf(a1.z); v[7] = f2bf(a1.w);
        *(short8*)&As[lr][lk] = v;
      } else {
        const short* A = (const short*)Ap;
        *(short8*)&As[lr][lk] = *(const short8*)(A + (size_t)rl * K + kk + lk);
      }
      *(short8*)&Bs[lr][lk] = *(const short8*)(Bw + (size_t)(n0 + lr) * K + kk + lk);
    }
    __syncthreads();
    short8 af[2], bfr[2];
#pragma unroll
    for (int i = 0; i < 2; i++) af[i] = *(short8*)&As[wm * 32 + i * 16 + l16][quad * 8];
#pragma unroll
    for (int j = 0; j < 2; j++) bfr[j] = *(short8*)&Bs[wn * 32 + j * 16 + l16][quad * 8];
#pragma unroll
    for (int i = 0; i < 2; i++)
#pragma unroll
      for (int j = 0; j < 2; j++)
        acc[i][j] = __builtin_amdgcn_mfma_f32_16x16x32_bf16(af[i], bfr[j], acc[i][j], 0, 0, 0);
  }
#pragma unroll
  for (int i = 0; i < 2; i++) {
#pragma unroll
    for (int j = 0; j < 2; j++) {
#pragma unroll
      for (int rr = 0; rr < 4; rr++) {
        int row = m0 + wm * 32 + i * 16 + quad * 4 + rr;
        int col = n0 + wn * 32 + j * 16 + l16;
        float v2 = acc[i][j][rr] + bias[col];
        if (OUT_SW) {
          int t = row >> 5, b = row & 31;
          int wg2 = b >> 4, bl = b & 15;
          int wv2 = col >> 6, ct2 = (col >> 4) & 3, q2 = (col >> 2) & 3, r2 = col & 3;
          size_t idx = (((((size_t)t * 2 + wg2) * 8 + wv2) * 4 + ct2) * 64 + (q2 * 16 + bl)) * 4 + r2;
          ((short*)Cp)[idx] = f2bf(v2);
        } else {
          size_t idx = ((size_t)(row & 31) * TT + (row >> 5)) * N + col;
          if (RESID) v2 += resid[idx];
          ((float*)Cp)[idx] = v2;
        }
      }
    }
  }
}

// ---------------- fused pipeline: scan0 || xin1-GEMM || scan1 ----------------
// blocks 0,1   : layer-0 scan (producer). Publishes flags[wg]=chunks done
//                (release-agent) after draining hall0 stores.
// blocks 4..67 : helper GEMM WGs. Per chunk c: wait flags[0..1]>=c+1, compute
//                one 128x64 tile of xin1 = hall0 @ W_in1^T + b_in1 (swizzled),
//                then release-add done1[c].
// blocks 2,3   : layer-1 scan (consumer). At chunk c waits done1[min(c+1,last)]
//                ==NHELP (covers the 1-step cross-chunk prefetch), overwrites
//                hall with h1 stream.
// Aliasing is safe: xin chunk c is rewritten only after scan0's release proves
// its chunk-c reads drained (vmcnt(0) covers loads); hall chunk c is rewritten
// by scan1 only after helpers' release proves their chunk c/c+1 reads drained.
// DAG pipeline with monotonic flags => no deadlock under any dispatch order.
__global__ __launch_bounds__(512, 2) void fused_pipeline(
    short* __restrict__ xin_sw, const short* __restrict__ Wrec0,
    const float* __restrict__ tau0, const short* __restrict__ Wrec1,
    const float* __restrict__ tau1, const short* __restrict__ Win1,
    const float* __restrict__ bin1, short* __restrict__ hall,
    unsigned* __restrict__ flags) {
  __shared__ short Wl[8][16][64][8];   // 128 KiB: scan weight frags / helper As+Bs
  __shared__ __align__(16) short hb[16][520];  // h state, bf16 (scan only)
  unsigned* done1 = flags + 16;
  int bid = blockIdx.x;
  int tid = threadIdx.x;

  if (bid >= 4) {
    // ================= helper role: streamed xin1 GEMM =================
    int hw = bid - 4;
    int mt = hw >> 3, nt = hw & 7;           // 8 x 8 tiles of 128x64 per chunk
    short (*As)[40] = (short (*)[40])(&Wl[0][0][0][0]);            // [128][40]
    short (*Bs)[40] = (short (*)[40])(&Wl[0][0][0][0] + 128 * 40); // [64][40]
    int w = tid >> 6, lane = tid & 63;
    int wm = w >> 1, wn = w & 1;             // wave grid 4x2 over 128x64
    int quad = lane >> 4, l16 = lane & 15;
    int lr = tid >> 2, lk = (tid & 3) * 8;
#pragma unroll 1
    for (int c = 0; c < NCHUNK; ++c) {
      unsigned want = (unsigned)(c + 1);
      if (tid == 0) {
        while (__hip_atomic_load(&flags[0], __ATOMIC_RELAXED, __HIP_MEMORY_SCOPE_AGENT) < want ||
               __hip_atomic_load(&flags[1], __ATOMIC_RELAXED, __HIP_MEMORY_SCOPE_AGENT) < want)
          __builtin_amdgcn_s_sleep(32);
      }
      __syncthreads();
      {
        unsigned f0 = __hip_atomic_load(&flags[0], __ATOMIC_ACQUIRE, __HIP_MEMORY_SCOPE_AGENT);
        asm volatile("" :: "v"(f0));  // keep the acquire (cache-inv) alive
      }
      int m0 = c * (CH * 32) + mt * 128;
      int n0 = nt * 64;
      f32x4 acc[2][2];
#pragma unroll
      for (int i = 0; i < 2; i++)
#pragma unroll
        for (int j = 0; j < 2; j++) acc[i][j] = (f32x4){0.f, 0.f, 0.f, 0.f};
      for (int kk = 0; kk < HH; kk += 32) {
        __syncthreads();
        *(short8*)&As[lr][lk] = *(const short8*)(hall + (size_t)(m0 + lr) * HH + kk + lk);
        if (tid < 256)
          *(short8*)&Bs[tid >> 2][lk] = *(const short8*)(Win1 + (size_t)(n0 + (tid >> 2)) * HH + kk + lk);
        __syncthreads();
        short8 af[2], bfr[2];
#pragma unroll
        for (int i = 0; i < 2; i++) af[i] = *(short8*)&As[wm * 32 + i * 16 + l16][quad * 8];
#pragma unroll
        for (int j = 0; j < 2; j++) bfr[j] = *(short8*)&Bs[wn * 32 + j * 16 + l16][quad * 8];
#pragma unroll
        for (int i = 0; i < 2; i++)
#pragma unroll
          for (int j = 0; j < 2; j++)
            acc[i][j] = __builtin_amdgcn_mfma_f32_16x16x32_bf16(af[i], bfr[j], acc[i][j], 0, 0, 0);
      }
#pragma unroll
      for (int i = 0; i < 2; i++) {
#pragma unroll
        for (int j = 0; j < 2; j++) {
#pragma unroll
          for (int rr = 0; rr < 4; rr++) {
            int row = m0 + wm * 32 + i * 16 + quad * 4 + rr;
            int col = n0 + wn * 32 + j * 16 + l16;
            float v2 = acc[i][j][rr] + bin1[col];
            int t = row >> 5, b = row & 31;
            int wg2 = b >> 4, bl = b & 15;
            int wv2 = col >> 6, ct2 = (col >> 4) & 3, q2 = (col >> 2) & 3, r2 = col & 3;
            size_t idx = (((((size_t)t * 2 + wg2) * 8 + wv2) * 4 + ct2) * 64 + (q2 * 16 + bl)) * 4 + r2;
            xin_sw[idx] = f2bf(v2);
          }
        }
      }
      asm volatile("s_waitcnt vmcnt(0)" ::: "memory");  // this wave's loads+stores done
      __syncthreads();                                   // all waves done
      if (tid == 0)
        __hip_atomic_fetch_add(&done1[c], 1u, __ATOMIC_RELEASE, __HIP_MEMORY_SCOPE_AGENT);
    }
    return;
  }

  // ================= scan role (layer 0: bid<2 produces; layer 1: consumes) =================
  int producer = (bid < 2);
  int wg = bid & 1;
  const short* Wrec = producer ? Wrec0 : Wrec1;
  const float* taup = producer ? tau0 : tau1;

  int wv = tid >> 6, lane = tid & 63;
  int q = lane >> 4, l16 = lane & 15;
  int c0 = wv * 64;

  for (int i = tid; i < 16 * 520 / 2; i += 512) ((int*)hb)[i] = 0;

  // A-operand frags: frag(ct,kc) = W[col=c0+ct*16+l16][kc*32+q*8 .. +8]
  short8 wreg[48];
#pragma unroll
  for (int ct = 0; ct < 4; ct++) {
    const short* wrow = Wrec + (size_t)(c0 + ct * 16 + l16) * HH;
#pragma unroll
    for (int kc = 0; kc < 12; kc++)
      wreg[ct * 12 + kc] = *(const short8*)(wrow + kc * 32 + q * 8);
#pragma unroll
    for (int kc = 12; kc < 16; kc++)
      *(short8*)&Wl[wv][ct * 4 + (kc - 12)][lane][0] = *(const short8*)(wrow + kc * 32 + q * 8);
  }
  // per-thread rates for its 16 cols (ct,r): col = c0 + ct*16 + q*4 + r
  float rate[16];
#pragma unroll
  for (int ct = 0; ct < 4; ct++)
#pragma unroll
    for (int r = 0; r < 4; r++) {
      float tc = taup[c0 + ct * 16 + q * 4 + r];
      tc = fminf(fmaxf(tc, 0.1f), 10.f);
      rate[ct * 4 + r] = 0.1f / tc;
    }
  float st[16];
#pragma unroll
  for (int i = 0; i < 16; i++) st[i] = 0.f;

  const short* xbase = xin_sw + (size_t)wg * 8192 + wv * 1024 + lane * 4;
  short* hallp = hall + ((size_t)wg * 16 + l16) * HH + c0 + q * 4;

  short4v xrA[4], xrB[4];
  __syncthreads();

#define STEP_BODY(T, XU, XP)                                                      \
  {                                                                               \
    int tn = ((T) + 1 < TT) ? (T) + 1 : (T);                                      \
    const short* xp_ = xbase + (size_t)tn * 16384;                                \
    _Pragma("unroll")                                                             \
    for (int ct = 0; ct < 4; ct++) XP[ct] = *(const short4v*)(xp_ + ct * 256);    \
    f32x4 acc[4];                                                                 \
    _Pragma("unroll")                                                             \
    for (int ct = 0; ct < 4; ct++) acc[ct] = (f32x4){0.f, 0.f, 0.f, 0.f};         \
    _Pragma("unroll")                                                             \
    for (int kc = 0; kc < 12; kc++) {                                             \
      short8 af = *(short8*)&hb[l16][kc * 32 + q * 8];                            \
      _Pragma("unroll")                                                           \
      for (int ct = 0; ct < 4; ct++)                                              \
        acc[ct] = __builtin_amdgcn_mfma_f32_16x16x32_bf16(wreg[ct * 12 + kc],     \
                                                          af, acc[ct], 0, 0, 0);  \
    }                                                                             \
    _Pragma("unroll")                                                             \
    for (int kc = 12; kc < 16; kc++) {                                            \
      short8 af = *(short8*)&hb[l16][kc * 32 + q * 8];                            \
      _Pragma("unroll")                                                           \
      for (int ct = 0; ct < 4; ct++) {                                            \
        short8 wf = *(short8*)&Wl[wv][ct * 4 + (kc - 12)][lane][0];               \
        acc[ct] = __builtin_amdgcn_mfma_f32_16x16x32_bf16(wf, af, acc[ct], 0, 0, 0); \
      }                                                                           \
    }                                                                             \
    barrier_lds(); /* all waves done reading hb */                                \
    short* hp_ = hallp + ((size_t)(T) * 32) * HH;                                 \
    _Pragma("unroll")                                                             \
    for (int ct = 0; ct < 4; ct++) {                                              \
      short4v hv;                                                                 \
      _Pragma("unroll")                                                           \
      for (int r = 0; r < 4; r++) {                                               \
        float u = acc[ct][r] + bf2f(XU[ct][r]);                                   \
        float v = u * 2.8853900817779268f;                                        \
        v = fminf(fmaxf(v, -30.f), 30.f);                                         \
        float e = __builtin_amdgcn_exp2f(v);                                      \
        float tg = (e - 1.f) * __builtin_amdgcn_rcpf(e + 1.f);                    \
        float h = st[ct * 4 + r];                                                 \
        h += rate[ct * 4 + r] * (tg - h);                                         \
        st[ct * 4 + r] = h;                                                       \
        hv[r] = f2bf(h);                                                          \
      }                                                                           \
      *(short4v*)&hb[l16][c0 + ct * 16 + q * 4] = hv;                             \
      *(short4v*)(hp_ + ct * 16) = hv;                                            \
    }                                                                             \
    barrier_lds(); /* hb(t+1) complete */                                         \
  }

#pragma unroll 1
  for (int c = 0; c < NCHUNK; ++c) {
    if (!producer) {
      // need chunks c and c+1 of xin1 (prefetch crosses the boundary by 1 step)
      int tgt = (c + 1 < NCHUNK) ? (c + 1) : (NCHUNK - 1);
      if (tid == 0) {
        while (__hip_atomic_load(&done1[tgt], __ATOMIC_RELAXED, __HIP_MEMORY_SCOPE_AGENT) < (unsigned)NHELP)
          __builtin_amdgcn_s_sleep(8);
      }
      __syncthreads();
      {
        unsigned f0 = __hip_atomic_load(&done1[tgt], __ATOMIC_ACQUIRE, __HIP_MEMORY_SCOPE_AGENT);
        asm volatile("" :: "v"(f0));  // keep acquire (cache-inv) alive per wave
      }
    }
    if (c == 0) {
#pragma unroll
      for (int ct = 0; ct < 4; ct++) xrA[ct] = *(const short4v*)(xbase + ct * 256);
    }
    int tb = c * CH;
#pragma unroll 1
    for (int tt = 0; tt < CH; tt += 2) {
      STEP_BODY(tb + tt, xrA, xrB);
      STEP_BODY(tb + tt + 1, xrB, xrA);
    }
    if (producer) {
      asm volatile("s_waitcnt vmcnt(0)" ::: "memory");  // this wave's hall stores + xin loads done
      __syncthreads();                                   // all waves drained
      if (tid == 0)
        __hip_atomic_store(&flags[wg], (unsigned)(c + 1), __ATOMIC_RELEASE, __HIP_MEMORY_SCOPE_AGENT);
    }
  }
#undef STEP_BODY
}

extern "C" void kernel_launch(void* const* d_in, const int* in_sizes, int n_in,
                              void* d_out, int out_size, void* d_ws, size_t ws_size,
                              hipStream_t stream) {
  const float* x      = (const float*)d_in[0];
  const float* W_in0  = (const float*)d_in[1];
  const float* b_in0  = (const float*)d_in[2];
  const float* W_rec0 = (const float*)d_in[3];
  const float* tau0   = (const float*)d_in[4];
  const float* W_in1  = (const float*)d_in[5];
  const float* b_in1  = (const float*)d_in[6];
  const float* W_rec1 = (const float*)d_in[7];
  const float* tau1   = (const float*)d_in[8];
  const float* W_out  = (const float*)d_in[9];
  const float* b_out  = (const float*)d_in[10];

  char* ws = (char*)d_ws;
  short* wb     = (short*)ws;                        // 2 MB bf16 weights
  unsigned* flags = (unsigned*)(ws + (2u << 20));    // pipeline flags (in 2MB gap)
  short* xin_sw = (short*)(ws + (4u << 20));         // 64 MB swizzled xin (xin0 then xin1, chunk-aliased)
  short* hall   = (short*)(ws + (68u << 20));        // 64 MB h stream (hall0 then hall1, chunk-aliased)

  short* wbin0  = wb;
  short* wbrec0 = wb + 131072;
  short* wbin1  = wb + 393216;
  short* wbrec1 = wb + 655360;
  short* wbout  = wb + 917504;

  convert_weights<<<4096, 256, 0, stream>>>(W_in0, W_rec0, W_in1, W_rec1, W_out, wb);
  hipMemsetAsync(flags, 0, 1024, stream);            // reset pipeline flags each launch

  dim3 g1(1024, 8);
  gemm_bt<1, 1, 0><<<g1, 256, 0, stream>>>((const void*)x, wbin0, b_in0, nullptr,
                                           (void*)xin_sw, BB * TT, HH, 256);

  // scan0 || streamed xin1 GEMM || scan1 (68 blocks, 1 CU each, all co-resident)
  fused_pipeline<<<4 + NHELP, 512, 0, stream>>>(xin_sw, wbrec0, tau0, wbrec1, tau1,
                                                wbin1, b_in1, hall, flags);

  dim3 g2(1024, 4);
  gemm_bt<0, 0, 1><<<g2, 256, 0, stream>>>((const void*)hall, wbout, b_out, x,
                                           d_out, BB * TT, 256, HH);
}

// Round 2
// 12021.207 us; speedup vs baseline: 1.4964x; 1.4964x over previous
//
#include <hip/hip_runtime.h>
#include <cstdint>
#include <cstddef>

typedef __attribute__((ext_vector_type(8))) short short8;
typedef __attribute__((ext_vector_type(4))) short short4v;
typedef __attribute__((ext_vector_type(4))) float f32x4;

#define TT 2048
#define BB 32
#define HH 512
#define CH 32                 // scan steps per pipeline chunk
#define NCHUNK (TT / CH)      // 64 chunks
#define NHELP 64              // helper WGs for the streamed xin1 GEMM

__device__ inline short f2bf(float f) {
  union { float f; unsigned u; } v; v.f = f;
  unsigned r = v.u + 0x7fffu + ((v.u >> 16) & 1u);
  return (short)(r >> 16);
}
__device__ inline float bf2f(short s) {
  union { unsigned u; float f; } v; v.u = ((unsigned)(unsigned short)s) << 16;
  return v.f;
}

union U64S4 { unsigned long long u; short4v v; };

// Cross-XCD coherent 8B accesses: agent-scope RELAXED atomics compile to
// sc1-flagged global ops that bypass the (non-coherent) per-XCD L2 and hit
// the Infinity-Cache coherence point directly. No buffer_wbl2/buffer_inv.
__device__ inline unsigned long long coh_ld64(const void* p) {
  return __hip_atomic_load((const unsigned long long*)p, __ATOMIC_RELAXED,
                           __HIP_MEMORY_SCOPE_AGENT);
}
__device__ inline void coh_st64(void* p, unsigned long long v) {
  __hip_atomic_store((unsigned long long*)p, v, __ATOMIC_RELAXED,
                     __HIP_MEMORY_SCOPE_AGENT);
}
// 2-byte coherent store for the helper's swizzled scatter epilogue.
__device__ inline void coh_st16(void* p, short v) {
  asm volatile("global_store_short %0, %1, off sc0 sc1"
               :: "v"(p), "v"((int)(unsigned short)v) : "memory");
}

// LDS-only barrier: drains ds ops (lgkmcnt) but NOT global loads/stores
// (vmcnt), so xin prefetches and hall stores stay in flight across steps.
__device__ inline void barrier_lds() {
  asm volatile("s_waitcnt lgkmcnt(0)\n\ts_barrier" ::: "memory");
}

// xin swizzled element index for (t, b, c):
//   wg=b>>4, bl=b&15(=l16), wv=c>>6, ct=(c>>4)&3, q=(c>>2)&3, r=c&3, lane=q*16+bl
//   idx = ((((t*2+wg)*8+wv)*4+ct)*64 + lane)*4 + r

// ---------------- weight fp32 -> bf16 conversion ----------------
__global__ void convert_weights(const float* __restrict__ w0, const float* __restrict__ w1,
                                const float* __restrict__ w2, const float* __restrict__ w3,
                                const float* __restrict__ w4, short* __restrict__ dst) {
  int i = blockIdx.x * 256 + threadIdx.x;
  if (i >= 1048576) return;
  const float* src; int off;
  if (i < 131072)      { src = w0; off = i; }
  else if (i < 393216) { src = w1; off = i - 131072; }
  else if (i < 655360) { src = w2; off = i - 393216; }
  else if (i < 917504) { src = w3; off = i - 655360; }
  else                 { src = w4; off = i - 917504; }
  dst[i] = f2bf(src[off]);
}

// ---------------- bf16 MFMA GEMM, C = A @ B^T + bias ----------------
template<int A_XF32, int OUT_SW, int RESID>
__global__ __launch_bounds__(256) void gemm_bt(const void* __restrict__ Ap,
    const short* __restrict__ Bw, const float* __restrict__ bias,
    const float* __restrict__ resid, void* __restrict__ Cp, int M, int N, int K) {
  __shared__ short As[64][40];
  __shared__ short Bs[64][40];
  int tid = threadIdx.x;
  int m0 = blockIdx.x * 64, n0 = blockIdx.y * 64;
  int w = tid >> 6, lane = tid & 63;
  int wm = w >> 1, wn = w & 1;
  int quad = lane >> 4, l16 = lane & 15;
  f32x4 acc[2][2];
#pragma unroll
  for (int i = 0; i < 2; i++)
#pragma unroll
    for (int j = 0; j < 2; j++) acc[i][j] = (f32x4){0.f, 0.f, 0.f, 0.f};
  int lr = tid >> 2, lk = (tid & 3) * 8;
  for (int kk = 0; kk < K; kk += 32) {
    __syncthreads();
    {
      int rl = m0 + lr;
      if (A_XF32) {
        const float* A = (const float*)Ap;
        size_t phys = ((size_t)(rl & 31) * TT + (rl >> 5)) * K;
        const float4* p = (const float4*)(A + phys + kk + lk);
        float4 a0 = p[0], a1 = p[1];
        short8 v;
        v[0] = f2bf(a0.x); v[1] = f2bf(a0.y); v[2] = f2bf(a0.z); v[3] = f2bf(a0.w);
        v[4] = f2bf(a1.x); v[5] = f2bf(a1.y); v[6] = f2bf(a1.z); v[7] = f2bf(a1.w);
        *(short8*)&As[lr][lk] = v;
      } else {
        const short* A = (const short*)Ap;
        *(short8*)&As[lr][lk] = *(const short8*)(A + (size_t)rl * K + kk + lk);
      }
      *(short8*)&Bs[lr][lk] = *(const short8*)(Bw + (size_t)(n0 + lr) * K + kk + lk);
    }
    __syncthreads();
    short8 af[2], bfr[2];
#pragma unroll
    for (int i = 0; i < 2; i++) af[i] = *(short8*)&As[wm * 32 + i * 16 + l16][quad * 8];
#pragma unroll
    for (int j = 0; j < 2; j++) bfr[j] = *(short8*)&Bs[wn * 32 + j * 16 + l16][quad * 8];
#pragma unroll
    for (int i = 0; i < 2; i++)
#pragma unroll
      for (int j = 0; j < 2; j++)
        acc[i][j] = __builtin_amdgcn_mfma_f32_16x16x32_bf16(af[i], bfr[j], acc[i][j], 0, 0, 0);
  }
#pragma unroll
  for (int i = 0; i < 2; i++) {
#pragma unroll
    for (int j = 0; j < 2; j++) {
#pragma unroll
      for (int rr = 0; rr < 4; rr++) {
        int row = m0 + wm * 32 + i * 16 + quad * 4 + rr;
        int col = n0 + wn * 32 + j * 16 + l16;
        float v2 = acc[i][j][rr] + bias[col];
        if (OUT_SW) {
          int t = row >> 5, b = row & 31;
          int wg2 = b >> 4, bl = b & 15;
          int wv2 = col >> 6, ct2 = (col >> 4) & 3, q2 = (col >> 2) & 3, r2 = col & 3;
          size_t idx = (((((size_t)t * 2 + wg2) * 8 + wv2) * 4 + ct2) * 64 + (q2 * 16 + bl)) * 4 + r2;
          ((short*)Cp)[idx] = f2bf(v2);
        } else {
          size_t idx = ((size_t)(row & 31) * TT + (row >> 5)) * N + col;
          if (RESID) v2 += resid[idx];
          ((float*)Cp)[idx] = v2;
        }
      }
    }
  }
}

// ---------------- fused pipeline: scan0 || xin1-GEMM || scan1 ----------------
// blocks 0,1   : layer-0 scan (producer). Per chunk: per-wave vmcnt(0) drain of
//                its sc1 hall stores, syncthreads, then RELAXED flag store.
// blocks 4..67 : helper GEMM WGs. Per chunk c: relaxed-poll flags[0..1]>=c+1,
//                read hall0 via sc1 loads, Win1 via normal (L2-cached) loads,
//                write swizzled xin1 via sc1 2B stores, drain, relaxed add done1[c].
// blocks 2,3   : layer-1 scan (consumer). Relaxed-polls done1[c+1]==NHELP, reads
//                xin1 via sc1 loads, overwrites hall with h1 via sc1 stores.
// All cross-XCD data moves through sc1 (agent-coherent) accesses => no
// buffer_wbl2 / buffer_inv anywhere; Win1 and private data stay L2-cached.
__global__ __launch_bounds__(512, 2) void fused_pipeline(
    short* __restrict__ xin_sw, const short* __restrict__ Wrec0,
    const float* __restrict__ tau0, const short* __restrict__ Wrec1,
    const float* __restrict__ tau1, const short* __restrict__ Win1,
    const float* __restrict__ bin1, short* __restrict__ hall,
    unsigned* __restrict__ flags) {
  __shared__ short Wl[8][16][64][8];   // 128 KiB: scan weight frags / helper As+Bs
  __shared__ __align__(16) short hb[16][520];  // h state, bf16 (scan only)
  unsigned* done1 = flags + 16;
  int bid = blockIdx.x;
  int tid = threadIdx.x;

  if (bid >= 4) {
    // ================= helper role: streamed xin1 GEMM =================
    int hw = bid - 4;
    int mt = hw >> 3, nt = hw & 7;           // 8 x 8 tiles of 128x64 per chunk
    short (*As)[40] = (short (*)[40])(&Wl[0][0][0][0]);            // [128][40]
    short (*Bs)[40] = (short (*)[40])(&Wl[0][0][0][0] + 128 * 40); // [64][40]
    int w = tid >> 6, lane = tid & 63;
    int wm = w >> 1, wn = w & 1;             // wave grid 4x2 over 128x64
    int quad = lane >> 4, l16 = lane & 15;
    int lr = tid >> 2, lk = (tid & 3) * 8;
#pragma unroll 1
    for (int c = 0; c < NCHUNK; ++c) {
      unsigned want = (unsigned)(c + 1);
      if (tid == 0) {
        while (__hip_atomic_load(&flags[0], __ATOMIC_RELAXED, __HIP_MEMORY_SCOPE_AGENT) < want ||
               __hip_atomic_load(&flags[1], __ATOMIC_RELAXED, __HIP_MEMORY_SCOPE_AGENT) < want)
          __builtin_amdgcn_s_sleep(32);
      }
      __syncthreads();
      int m0 = c * (CH * 32) + mt * 128;
      int n0 = nt * 64;
      f32x4 acc[2][2];
#pragma unroll
      for (int i = 0; i < 2; i++)
#pragma unroll
        for (int j = 0; j < 2; j++) acc[i][j] = (f32x4){0.f, 0.f, 0.f, 0.f};
      for (int kk = 0; kk < HH; kk += 32) {
        __syncthreads();
        {
          const short* arow = hall + (size_t)(m0 + lr) * HH + kk + lk;
          unsigned long long a0 = coh_ld64(arow);
          unsigned long long a1 = coh_ld64(arow + 4);
          *(unsigned long long*)&As[lr][lk] = a0;
          *(unsigned long long*)&As[lr][lk + 4] = a1;
        }
        if (tid < 256)
          *(short8*)&Bs[tid >> 2][lk] = *(const short8*)(Win1 + (size_t)(n0 + (tid >> 2)) * HH + kk + lk);
        __syncthreads();
        short8 af[2], bfr[2];
#pragma unroll
        for (int i = 0; i < 2; i++) af[i] = *(short8*)&As[wm * 32 + i * 16 + l16][quad * 8];
#pragma unroll
        for (int j = 0; j < 2; j++) bfr[j] = *(short8*)&Bs[wn * 32 + j * 16 + l16][quad * 8];
#pragma unroll
        for (int i = 0; i < 2; i++)
#pragma unroll
          for (int j = 0; j < 2; j++)
            acc[i][j] = __builtin_amdgcn_mfma_f32_16x16x32_bf16(af[i], bfr[j], acc[i][j], 0, 0, 0);
      }
#pragma unroll
      for (int i = 0; i < 2; i++) {
#pragma unroll
        for (int j = 0; j < 2; j++) {
#pragma unroll
          for (int rr = 0; rr < 4; rr++) {
            int row = m0 + wm * 32 + i * 16 + quad * 4 + rr;
            int col = n0 + wn * 32 + j * 16 + l16;
            float v2 = acc[i][j][rr] + bin1[col];
            int t = row >> 5, b = row & 31;
            int wg2 = b >> 4, bl = b & 15;
            int wv2 = col >> 6, ct2 = (col >> 4) & 3, q2 = (col >> 2) & 3, r2 = col & 3;
            size_t idx = (((((size_t)t * 2 + wg2) * 8 + wv2) * 4 + ct2) * 64 + (q2 * 16 + bl)) * 4 + r2;
            coh_st16(&xin_sw[idx], f2bf(v2));
          }
        }
      }
      asm volatile("s_waitcnt vmcnt(0)" ::: "memory");  // this wave's sc1 stores at IC
      __syncthreads();                                   // all waves drained
      if (tid == 0)
        __hip_atomic_fetch_add(&done1[c], 1u, __ATOMIC_RELAXED, __HIP_MEMORY_SCOPE_AGENT);
    }
    return;
  }

  // ================= scan role (layer 0: bid<2 produces; layer 1: consumes) =================
  int producer = (bid < 2);
  int wg = bid & 1;
  const short* Wrec = producer ? Wrec0 : Wrec1;
  const float* taup = producer ? tau0 : tau1;

  int wv = tid >> 6, lane = tid & 63;
  int q = lane >> 4, l16 = lane & 15;
  int c0 = wv * 64;

  for (int i = tid; i < 16 * 520 / 2; i += 512) ((int*)hb)[i] = 0;

  // A-operand frags: frag(ct,kc) = W[col=c0+ct*16+l16][kc*32+q*8 .. +8]
  short8 wreg[48];
#pragma unroll
  for (int ct = 0; ct < 4; ct++) {
    const short* wrow = Wrec + (size_t)(c0 + ct * 16 + l16) * HH;
#pragma unroll
    for (int kc = 0; kc < 12; kc++)
      wreg[ct * 12 + kc] = *(const short8*)(wrow + kc * 32 + q * 8);
#pragma unroll
    for (int kc = 12; kc < 16; kc++)
      *(short8*)&Wl[wv][ct * 4 + (kc - 12)][lane][0] = *(const short8*)(wrow + kc * 32 + q * 8);
  }
  // per-thread rates for its 16 cols (ct,r): col = c0 + ct*16 + q*4 + r
  float rate[16];
#pragma unroll
  for (int ct = 0; ct < 4; ct++)
#pragma unroll
    for (int r = 0; r < 4; r++) {
      float tc = taup[c0 + ct * 16 + q * 4 + r];
      tc = fminf(fmaxf(tc, 0.1f), 10.f);
      rate[ct * 4 + r] = 0.1f / tc;
    }
  float st[16];
#pragma unroll
  for (int i = 0; i < 16; i++) st[i] = 0.f;

  const short* xbase = xin_sw + (size_t)wg * 8192 + wv * 1024 + lane * 4;
  short* hallp = hall + ((size_t)wg * 16 + l16) * HH + c0 + q * 4;

  short4v xrA[4], xrB[4];
  __syncthreads();

#define STEP_BODY(T, XU, XP)                                                      \
  {                                                                               \
    int tn = ((T) + 1 < TT) ? (T) + 1 : (T);                                      \
    const short* xp_ = xbase + (size_t)tn * 16384;                                \
    _Pragma("unroll")                                                             \
    for (int ct = 0; ct < 4; ct++) {                                              \
      U64S4 u_; u_.u = coh_ld64(xp_ + ct * 256);                                  \
      XP[ct] = u_.v;                                                              \
    }                                                                             \
    f32x4 acc[4];                                                                 \
    _Pragma("unroll")                                                             \
    for (int ct = 0; ct < 4; ct++) acc[ct] = (f32x4){0.f, 0.f, 0.f, 0.f};         \
    _Pragma("unroll")                                                             \
    for (int kc = 0; kc < 12; kc++) {                                             \
      short8 af = *(short8*)&hb[l16][kc * 32 + q * 8];                            \
      _Pragma("unroll")                                                           \
      for (int ct = 0; ct < 4; ct++)                                              \
        acc[ct] = __builtin_amdgcn_mfma_f32_16x16x32_bf16(wreg[ct * 12 + kc],     \
                                                          af, acc[ct], 0, 0, 0);  \
    }                                                                             \
    _Pragma("unroll")                                                             \
    for (int kc = 12; kc < 16; kc++) {                                            \
      short8 af = *(short8*)&hb[l16][kc * 32 + q * 8];                            \
      _Pragma("unroll")                                                           \
      for (int ct = 0; ct < 4; ct++) {                                            \
        short8 wf = *(short8*)&Wl[wv][ct * 4 + (kc - 12)][lane][0];               \
        acc[ct] = __builtin_amdgcn_mfma_f32_16x16x32_bf16(wf, af, acc[ct], 0, 0, 0); \
      }                                                                           \
    }                                                                             \
    barrier_lds(); /* all waves done reading hb */                                \
    short* hp_ = hallp + ((size_t)(T) * 32) * HH;                                 \
    _Pragma("unroll")                                                             \
    for (int ct = 0; ct < 4; ct++) {                                              \
      short4v hv;                                                                 \
      _Pragma("unroll")                                                           \
      for (int r = 0; r < 4; r++) {                                               \
        float u = acc[ct][r] + bf2f(XU[ct][r]);                                   \
        float v = u * 2.8853900817779268f;                                        \
        v = fminf(fmaxf(v, -30.f), 30.f);                                         \
        float e = __builtin_amdgcn_exp2f(v);                                      \
        float tg = (e - 1.f) * __builtin_amdgcn_rcpf(e + 1.f);                    \
        float h = st[ct * 4 + r];                                                 \
        h += rate[ct * 4 + r] * (tg - h);                                         \
        st[ct * 4 + r] = h;                                                       \
        hv[r] = f2bf(h);                                                          \
      }                                                                           \
      *(short4v*)&hb[l16][c0 + ct * 16 + q * 4] = hv;                             \
      { U64S4 hu_; hu_.v = hv; coh_st64(hp_ + ct * 16, hu_.u); }                  \
    }                                                                             \
    barrier_lds(); /* hb(t+1) complete */                                         \
  }

#pragma unroll 1
  for (int c = 0; c < NCHUNK; ++c) {
    if (!producer) {
      // need chunks c and c+1 of xin1 (prefetch crosses the boundary by 1 step)
      int tgt = (c + 1 < NCHUNK) ? (c + 1) : (NCHUNK - 1);
      if (tid == 0) {
        while (__hip_atomic_load(&done1[tgt], __ATOMIC_RELAXED, __HIP_MEMORY_SCOPE_AGENT) < (unsigned)NHELP)
          __builtin_amdgcn_s_sleep(8);
      }
      __syncthreads();
    }
    if (c == 0) {
#pragma unroll
      for (int ct = 0; ct < 4; ct++) {
        U64S4 u_; u_.u = coh_ld64(xbase + ct * 256);
        xrA[ct] = u_.v;
      }
    }
    int tb = c * CH;
#pragma unroll 1
    for (int tt = 0; tt < CH; tt += 2) {
      STEP_BODY(tb + tt, xrA, xrB);
      STEP_BODY(tb + tt + 1, xrB, xrA);
    }
    if (producer) {
      asm volatile("s_waitcnt vmcnt(0)" ::: "memory");  // this wave's sc1 hall stores at IC
      __syncthreads();                                   // all waves drained
      if (tid == 0)
        __hip_atomic_store(&flags[wg], (unsigned)(c + 1), __ATOMIC_RELAXED, __HIP_MEMORY_SCOPE_AGENT);
    }
  }
#undef STEP_BODY
}

extern "C" void kernel_launch(void* const* d_in, const int* in_sizes, int n_in,
                              void* d_out, int out_size, void* d_ws, size_t ws_size,
                              hipStream_t stream) {
  const float* x      = (const float*)d_in[0];
  const float* W_in0  = (const float*)d_in[1];
  const float* b_in0  = (const float*)d_in[2];
  const float* W_rec0 = (const float*)d_in[3];
  const float* tau0   = (const float*)d_in[4];
  const float* W_in1  = (const float*)d_in[5];
  const float* b_in1  = (const float*)d_in[6];
  const float* W_rec1 = (const float*)d_in[7];
  const float* tau1   = (const float*)d_in[8];
  const float* W_out  = (const float*)d_in[9];
  const float* b_out  = (const float*)d_in[10];

  char* ws = (char*)d_ws;
  short* wb     = (short*)ws;                        // 2 MB bf16 weights
  unsigned* flags = (unsigned*)(ws + (2u << 20));    // pipeline flags (in 2MB gap)
  short* xin_sw = (short*)(ws + (4u << 20));         // 64 MB swizzled xin (xin0 then xin1, chunk-aliased)
  short* hall   = (short*)(ws + (68u << 20));        // 64 MB h stream (hall0 then hall1, chunk-aliased)

  short* wbin0  = wb;
  short* wbrec0 = wb + 131072;
  short* wbin1  = wb + 393216;
  short* wbrec1 = wb + 655360;
  short* wbout  = wb + 917504;

  convert_weights<<<4096, 256, 0, stream>>>(W_in0, W_rec0, W_in1, W_rec1, W_out, wb);
  hipMemsetAsync(flags, 0, 1024, stream);            // reset pipeline flags each launch

  dim3 g1(1024, 8);
  gemm_bt<1, 1, 0><<<g1, 256, 0, stream>>>((const void*)x, wbin0, b_in0, nullptr,
                                           (void*)xin_sw, BB * TT, HH, 256);

  // scan0 || streamed xin1 GEMM || scan1 (68 blocks, 1 CU each, all co-resident)
  fused_pipeline<<<4 + NHELP, 512, 0, stream>>>(xin_sw, wbrec0, tau0, wbrec1, tau1,
                                                wbin1, b_in1, hall, flags);

  dim3 g2(1024, 4);
  gemm_bt<0, 0, 1><<<g2, 256, 0, stream>>>((const void*)hall, wbout, b_out, x,
                                           d_out, BB * TT, 256, HH);
}